// Round 11
// baseline (187.223 us; speedup 1.0000x reference)
//
#include <hip/hip_runtime.h>
#include <hip/hip_bf16.h>

// MDN NLL, fully fused. N=524288 Dx=128 Dt=64 M=32 K=8.
// Memory-bound target: 470 MB reads -> ~75us floor at 6.3 TB/s.
// R11 = R10 (column-split waves: 16 waves, wave = (expert kx=wv&7, half
// hh=wv>>3), bfrag=32 regs, transposed MFMA) with:
//  - ONE lgkm barrier/iter: llp double-buffered; commit before barrier;
//    LSE after. Gate MFMA hoisted pre-barrier (independent of llp) and
//    deduplicated to waves 0-1 (R10 had 4 waves doing each half twice).
//  - Padded LDS rows instead of XOR swizzle: xs stride 272B, ts 144B,
//    identity chunks. Row stride = 4 banks (mod 32) rotates rows across
//    groups -> natural conflict-free b128 pattern (m134). R10's 3-bit XOR
//    made 8-way clusters (9.4M conflicts).
//  - y read direct from global in the epilogue (no LDS, no stager role).
// Hard fact: 1024-thr block => 4 waves/SIMD co-resident => <=128 unified
// regs regardless of launch_bounds. bfrag=32 keeps demand near the cap.

#define NN 524288
#define DX 128
#define DT 64
#define MDIM 32
#define KEXP 8
#define TILE_R 32
#define THREADS 1024
#define GRID_MAIN 512
#define TILES_TOTAL (NN / TILE_R)        // 16384
#define TPB (TILES_TOTAL / GRID_MAIN)    // 32

#define XS_STRIDE 136   // ushorts per row (272 B)
#define TS_STRIDE 72    // ushorts per row (144 B)

typedef __bf16 bf16x8 __attribute__((ext_vector_type(8)));
typedef float f32x4 __attribute__((ext_vector_type(4)));

__device__ __forceinline__ bf16x8 cvt8(const f32x4 a, const f32x4 b) {
  bf16x8 r;
  r[0] = (__bf16)a[0]; r[1] = (__bf16)a[1]; r[2] = (__bf16)a[2]; r[3] = (__bf16)a[3];
  r[4] = (__bf16)b[0]; r[5] = (__bf16)b[1]; r[6] = (__bf16)b[2]; r[7] = (__bf16)b[3];
  return r;
}

#define MFMA16(a, b, c) __builtin_amdgcn_mfma_f32_16x16x32_bf16(a, b, c, 0, 0, 0)

// LDS-only barrier: global loads stay in flight across it (rule 18 fence).
#define B_LDS() do { \
  asm volatile("s_waitcnt lgkmcnt(0)" ::: "memory"); \
  __builtin_amdgcn_s_barrier(); \
  __builtin_amdgcn_sched_barrier(0); } while (0)

__global__ __launch_bounds__(THREADS, 4) void mdn_main(
    const float* __restrict__ x, const float* __restrict__ t,
    const float* __restrict__ y, const float* __restrict__ Wm,
    const float* __restrict__ bm, const float* __restrict__ Wv,
    const float* __restrict__ bv, const float* __restrict__ Wg,
    const float* __restrict__ bg, float* __restrict__ partials,
    float* __restrict__ out_atomic)
{
  __shared__ __align__(16) unsigned short xs_l[2][TILE_R * XS_STRIDE]; // 17 KB
  __shared__ __align__(16) unsigned short ts_l[2][TILE_R * TS_STRIDE]; // 9 KB
  __shared__ __align__(16) unsigned short wg_lds[2 * 64 * 8];          // 2 KB
  __shared__ float llp[2][TILE_R * 20];                                // 5 KB
  __shared__ float red_s[16];

  const int tid = threadIdx.x;
  const int lane = tid & 63;
  const int wv = tid >> 6;        // 0..15
  const int l15 = lane & 15;
  const int lhi = lane >> 4;      // 0..3
  const int kx = wv & 7;          // expert
  const int hh = wv >> 3;         // column half (m-cols hh*16..+16)

  // ---- staging roles (identity chunk map; padding does the bank spread) --
  const bool is_x = (tid < 512);
  const bool is_t = (tid >= 512 && tid < 768);
  const float* st_base = nullptr;
  int st_stride = 0, st_ldsoff = 0;
  if (is_x) {
    const int r = tid >> 4, c = tid & 15;
    st_base = x + (size_t)r * DX + c * 8;
    st_stride = TILE_R * DX;
    st_ldsoff = r * 272 + c * 16;            // bytes
  } else if (is_t) {
    const int u = tid - 512, r = u >> 3, c = u & 7;
    st_base = t + (size_t)r * DT + c * 8;
    st_stride = TILE_R * DT;
    st_ldsoff = r * 144 + c * 16;            // bytes
  }

  f32x4 sa, sb;
  auto issue = [&](int tile) {
    if (tid < 768) {
      const float* p = st_base + (size_t)tile * st_stride;
      sa = *(const f32x4*)p;
      sb = *(const f32x4*)(p + 4);
    }
  };
  auto commit = [&](int buf) {
    if (is_x)      *(bf16x8*)((char*)xs_l[buf] + st_ldsoff) = cvt8(sa, sb);
    else if (is_t) *(bf16x8*)((char*)ts_l[buf] + st_ldsoff) = cvt8(sa, sb);
  };

  const int first = blockIdx.x * TPB;
  issue(first);    // tile-0 loads in flight under the weight prologue

  // biases: lane's 4 m's = hh*16 + lhi*4 + j
  const f32x4 bmean = *(const f32x4*)&bm[kx * MDIM + hh * 16 + lhi * 4];
  const f32x4 blv   = *(const f32x4*)&bv[kx * MDIM + hh * 16 + lhi * 4];
  f32x4 bgv = {0.f, 0.f, 0.f, 0.f};
  if (wv < 2) bgv = *(const f32x4*)&bg[(lhi & 1) * 4];

  // W fragments (A-operand, transposed MFMA): ct 0 = mean, 1 = logvar;
  // cols = hh*16 + l15; k = lhi*8 + i.  8 frags = 32 regs.
  bf16x8 bfrag[2][4];
  #pragma unroll
  for (int ct = 0; ct < 2; ++ct) {
    const float* W = (ct ? Wv : Wm) + (size_t)kx * (DX * MDIM);
    const int mcol = hh * 16 + l15;
    #pragma unroll
    for (int kk = 0; kk < 4; ++kk) {
      bf16x8 tmp;
      #pragma unroll
      for (int i = 0; i < 8; ++i)
        tmp[i] = (__bf16)W[(kk * 32 + lhi * 8 + i) * MDIM + mcol];
      bfrag[ct][kk] = tmp;
    }
  }
  // Gate weights -> LDS (one wave; rows >= KEXP zero-padded)
  if (wv == 15) {
    #pragma unroll
    for (int kk = 0; kk < 2; ++kk) {
      bf16x8 tmp;
      #pragma unroll
      for (int i = 0; i < 8; ++i) {
        const int d = kk * 32 + lhi * 8 + i;
        tmp[i] = (__bf16)((l15 < KEXP) ? Wg[d * KEXP + l15] : 0.f);
      }
      *(bf16x8*)((char*)wg_lds + (kk * 64 + lane) * 16) = tmp;
    }
  }

  commit(0);
  B_LDS();        // tile 0 + wg visible

  float loss_acc = 0.f;
  const float HL2PI = 0.91893853320467274f;   // 0.5*log(2*pi)

  for (int it = 0; it < TPB; ++it) {
    const int cur = it & 1;
    const int row0 = (first + it) * TILE_R;
    issue(first + ((it + 1 < TPB) ? it + 1 : it));   // next tile, early

    // ---- gate MFMA (waves 0-1; independent of llp; overlaps experts) ----
    f32x4 lgv = {0.f, 0.f, 0.f, 0.f};
    if (wv < 2) {
      const int rr = wv * 16 + l15;
      f32x4 g = {0.f, 0.f, 0.f, 0.f};
      #pragma unroll
      for (int kk = 0; kk < 2; ++kk) {
        const bf16x8 tf = *(const bf16x8*)((const char*)ts_l[cur] + rr * 144 + (kk * 4 + lhi) * 16);
        const bf16x8 wf = *(const bf16x8*)((const char*)wg_lds + (kk * 64 + lane) * 16);
        g = MFMA16(wf, tf, g);
      }
      #pragma unroll
      for (int j = 0; j < 4; ++j) lgv[j] = g[j] + bgv[j];
    }

    // ---- expert MFMAs + half-column Gaussian-LL ----
    const unsigned short* xc = xs_l[cur];
    #pragma unroll
    for (int rt = 0; rt < 2; ++rt) {
      const int rr = rt * 16 + l15;     // sample (B-col = l15)
      f32x4 acc0 = bmean, acc1 = blv;
      #pragma unroll
      for (int kk = 0; kk < 4; ++kk) {
        const bf16x8 af = *(const bf16x8*)((const char*)xc + rr * 272 + (kk * 4 + lhi) * 16);
        acc0 = MFMA16(bfrag[0][kk], af, acc0);
        acc1 = MFMA16(bfrag[1][kk], af, acc1);
      }
      // D: col = l15 = sample, row = lhi*4+j = m (within half hh)
      const f32x4 y4 = *(const f32x4*)&y[(size_t)(row0 + rr) * MDIM + hh * 16 + lhi * 4];
      float part = 0.f;
      #pragma unroll
      for (int j = 0; j < 4; ++j) {
        const float d = y4[j] - acc0[j];
        part += d * d * (0.5f * __expf(-acc1[j])) + 0.5f * acc1[j];
      }
      part += __shfl_xor(part, 16);
      part += __shfl_xor(part, 32);
      if (lhi == 0) llp[cur][rr * 20 + hh * 8 + kx] = -(part + 16.0f * HL2PI);
    }

    commit(cur ^ 1);   // write next tile (waits its own loads via vmcnt)
    B_LDS();           // the ONE barrier: llp[cur] + staged buffers visible

    // ---- LSE over experts (waves 0-1): in-lane over 4 k's + 1 shfl ----
    if (wv < 2) {
      const int rr = wv * 16 + l15;
      const f32x4 lvA = *(const f32x4*)&llp[cur][rr * 20 + (lhi & 1) * 4];
      const f32x4 lvB = *(const f32x4*)&llp[cur][rr * 20 + 8 + (lhi & 1) * 4];
      f32x4 a4;
      #pragma unroll
      for (int j = 0; j < 4; ++j) a4[j] = lgv[j] + lvA[j] + lvB[j];
      float mg = fmaxf(fmaxf(lgv[0], lgv[1]), fmaxf(lgv[2], lgv[3]));
      float ma = fmaxf(fmaxf(a4[0], a4[1]), fmaxf(a4[2], a4[3]));
      mg = fmaxf(mg, __shfl_xor(mg, 16));
      ma = fmaxf(ma, __shfl_xor(ma, 16));
      float eg = __expf(lgv[0] - mg) + __expf(lgv[1] - mg)
               + __expf(lgv[2] - mg) + __expf(lgv[3] - mg);
      float ea = __expf(a4[0] - ma) + __expf(a4[1] - ma)
               + __expf(a4[2] - ma) + __expf(a4[3] - ma);
      eg += __shfl_xor(eg, 16);
      ea += __shfl_xor(ea, 16);
      // lanes lhi>=2 hold garbage (llp cols 16..19 / duplicate): the shfl(16)
      // pairs lhi0<->lhi1 and lhi2<->lhi3; accumulate only from lhi==0.
      if (lhi == 0)
        loss_acc += (mg + __logf(eg)) - (ma + __logf(ea));
    }
  }

  // block reduction of loss
  loss_acc += __shfl_xor(loss_acc, 1);
  loss_acc += __shfl_xor(loss_acc, 2);
  loss_acc += __shfl_xor(loss_acc, 4);
  loss_acc += __shfl_xor(loss_acc, 8);
  loss_acc += __shfl_xor(loss_acc, 16);
  loss_acc += __shfl_xor(loss_acc, 32);
  if (lane == 0) red_s[wv] = loss_acc;
  __syncthreads();
  if (tid == 0) {
    float s = 0.f;
    #pragma unroll
    for (int w = 0; w < 16; ++w) s += red_s[w];
    if (partials) partials[blockIdx.x] = s;
    else atomicAdd(out_atomic, s);
  }
}

__global__ void mdn_reg(const float* __restrict__ Wm, const float* __restrict__ Wv,
                        const float* __restrict__ Wg, float* __restrict__ partials,
                        float* __restrict__ out_atomic)
{
  __shared__ float red[4];
  const int gid = blockIdx.x * 256 + threadIdx.x;
  const int stride = 64 * 256;
  float s = 0.f;
  for (int i = gid; i < DX * MDIM * KEXP; i += stride) { float w = Wm[i]; s += w * w; }
  for (int i = gid; i < DX * MDIM * KEXP; i += stride) { float w = Wv[i]; s += w * w; }
  for (int i = gid; i < DT * KEXP; i += stride)        { float w = Wg[i]; s += w * w; }
  s += __shfl_xor(s, 1);
  s += __shfl_xor(s, 2);
  s += __shfl_xor(s, 4);
  s += __shfl_xor(s, 8);
  s += __shfl_xor(s, 16);
  s += __shfl_xor(s, 32);
  if ((threadIdx.x & 63) == 0) red[threadIdx.x >> 6] = s;
  __syncthreads();
  if (threadIdx.x == 0) {
    float b = red[0] + red[1] + red[2] + red[3];
    if (partials) partials[GRID_MAIN + blockIdx.x] = b;
    else atomicAdd(out_atomic, b);
  }
}

__global__ void mdn_final(const float* __restrict__ partials, float* __restrict__ out)
{
  __shared__ float red[4];
  float s = 0.f;
  for (int i = threadIdx.x; i < GRID_MAIN + 64; i += 256) s += partials[i];
  s += __shfl_xor(s, 1);
  s += __shfl_xor(s, 2);
  s += __shfl_xor(s, 4);
  s += __shfl_xor(s, 8);
  s += __shfl_xor(s, 16);
  s += __shfl_xor(s, 32);
  if ((threadIdx.x & 63) == 0) red[threadIdx.x >> 6] = s;
  __syncthreads();
  if (threadIdx.x == 0) out[0] = red[0] + red[1] + red[2] + red[3];
}

extern "C" void kernel_launch(void* const* d_in, const int* in_sizes, int n_in,
                              void* d_out, int out_size, void* d_ws, size_t ws_size,
                              hipStream_t stream)
{
  const float* x  = (const float*)d_in[0];
  const float* t  = (const float*)d_in[1];
  const float* y  = (const float*)d_in[2];
  const float* Wm = (const float*)d_in[3];
  const float* bm = (const float*)d_in[4];
  const float* Wv = (const float*)d_in[5];
  const float* bv = (const float*)d_in[6];
  const float* Wg = (const float*)d_in[7];
  const float* bg = (const float*)d_in[8];
  float* out = (float*)d_out;

  if (ws_size >= (GRID_MAIN + 64) * sizeof(float)) {
    float* partials = (float*)d_ws;
    mdn_main<<<GRID_MAIN, THREADS, 0, stream>>>(x, t, y, Wm, bm, Wv, bv, Wg, bg,
                                                partials, nullptr);
    mdn_reg<<<64, 256, 0, stream>>>(Wm, Wv, Wg, partials, nullptr);
    mdn_final<<<1, 256, 0, stream>>>(partials, out);
  } else {
    hipMemsetAsync(out, 0, sizeof(float), stream);
    mdn_main<<<GRID_MAIN, THREADS, 0, stream>>>(x, t, y, Wm, bm, Wv, bv, Wg, bg,
                                                nullptr, out);
    mdn_reg<<<64, 256, 0, stream>>>(Wm, Wv, Wg, nullptr, out);
  }
}

// Round 12
// 183.835 us; speedup vs baseline: 1.0184x; 1.0184x over previous
//
#include <hip/hip_runtime.h>
#include <hip/hip_bf16.h>

// MDN NLL, fully fused. N=524288 Dx=128 Dt=64 M=32 K=8.
// Memory-bound target: 470 MB reads -> ~75us floor at 6.3 TB/s.
// R12 = R10 (best, 150us: column-split 16 waves, wave=(kx=wv&7, hh=wv>>3),
// bfrag=32 regs, transposed MFMA, gate+LSE on waves 0-3, 2 barriers/iter)
// with ONE change: staging via global_load_lds DMA (f32, pre-swizzled
// sources, counted vmcnt(2)/vmcnt(1), dbuf) instead of reg-staging.
// Removes the ~14 staging regs that spilled at the hard 128-reg cap
// (1024 thr => 4 waves/SIMD co-resident, launch_bounds can't lift it).
// cvt f32->bf16 moves back into the MFMA phase (VALU has headroom).
// R11 lessons: padding-vs-XOR didn't move conflicts (9.4M identical ->
// counter dominated by shuffles, not tile reads); y direct-in-epilogue
// exposes latency (R4 mistake); dedup to 2 waves lengthens critical path.

#define NN 524288
#define DX 128
#define DT 64
#define MDIM 32
#define KEXP 8
#define TILE_R 32
#define THREADS 1024
#define GRID_MAIN 512
#define TILES_TOTAL (NN / TILE_R)        // 16384
#define TPB (TILES_TOTAL / GRID_MAIN)    // 32

typedef __bf16 bf16x8 __attribute__((ext_vector_type(8)));
typedef float f32x4 __attribute__((ext_vector_type(4)));

__device__ __forceinline__ void glds16(const float* g, float* l) {
  __builtin_amdgcn_global_load_lds(
      (const __attribute__((address_space(1))) unsigned int*)g,
      (__attribute__((address_space(3))) unsigned int*)l, 16, 0, 0);
}

__device__ __forceinline__ bf16x8 cvt8(const f32x4 a, const f32x4 b) {
  bf16x8 r;
  r[0] = (__bf16)a[0]; r[1] = (__bf16)a[1]; r[2] = (__bf16)a[2]; r[3] = (__bf16)a[3];
  r[4] = (__bf16)b[0]; r[5] = (__bf16)b[1]; r[6] = (__bf16)b[2]; r[7] = (__bf16)b[3];
  return r;
}

#define MFMA16(a, b, c) __builtin_amdgcn_mfma_f32_16x16x32_bf16(a, b, c, 0, 0, 0)

// LDS-only barrier: DMA stays in flight across it (rule 18 fence).
#define B_LDS() do { \
  asm volatile("s_waitcnt lgkmcnt(0)" ::: "memory"); \
  __builtin_amdgcn_s_barrier(); \
  __builtin_amdgcn_sched_barrier(0); } while (0)

__global__ __launch_bounds__(THREADS, 4) void mdn_main(
    const float* __restrict__ x, const float* __restrict__ t,
    const float* __restrict__ y, const float* __restrict__ Wm,
    const float* __restrict__ bm, const float* __restrict__ Wv,
    const float* __restrict__ bv, const float* __restrict__ Wg,
    const float* __restrict__ bg, float* __restrict__ partials,
    float* __restrict__ out_atomic)
{
  __shared__ float xs2[2][TILE_R * DX];                         // 2 x 16 KB
  __shared__ float ts2[2][TILE_R * DT];                         // 2 x 8 KB
  __shared__ float ys2[2][TILE_R * MDIM];                       // 2 x 4 KB
  __shared__ __align__(16) unsigned short wg_lds[2 * 64 * 8];   // 2 KB
  __shared__ float llp[TILE_R * 20];                            // 2.5 KB
  __shared__ float red_s[16];

  const int tid = threadIdx.x;
  const int lane = tid & 63;
  const int wv = tid >> 6;        // 0..15
  const int l15 = lane & 15;
  const int lhi = lane >> 4;      // 0..3
  const int swz = l15 & 7;
  const int kx = wv & 7;          // expert
  const int hh = wv >> 3;         // column half (m-cols hh*16..+16)

  // ---- DMA geometry (16B chunks, involution-preswizzled sources) ----
  // x: 1024 chunks, every thread 1.  t: 512 chunks, waves 0-7.
  // y: 256 chunks, waves 8-11.
  const int chx = tid;
  const int xr = chx >> 5;
  const int x_src = xr * DX + (((chx & 31) ^ (xr & 7)) << 2);
  const int x_dst = chx * 4;                       // floats
  const int ut = tid;                              // valid when wv<8
  const int tr = ut >> 4;
  const int t_src = tr * DT + (((ut & 15) ^ (tr & 7)) << 2);
  const int t_dst = ut * 4;
  const int uy = tid - 512;                        // valid when 8<=wv<12
  const int yr = uy >> 3;
  const int y_src = yr * MDIM + (((uy & 7) ^ (yr & 7)) << 2);
  const int y_dst = uy * 4;

  const int first = blockIdx.x * TPB;

  auto issue_batch = [&](int tile, int buf) {
    const size_t base = (size_t)tile * TILE_R;
    glds16(x + base * DX + x_src, &xs2[buf][x_dst]);
    if (wv < 8)                 glds16(t + base * DT + t_src, &ts2[buf][t_dst]);
    else if (wv < 12)           glds16(y + base * MDIM + y_src, &ys2[buf][y_dst]);
  };

  issue_batch(first, 0);   // tile-0 DMA under the weight prologue

  // biases: lane's 4 m's = hh*16 + lhi*4 + j
  const f32x4 bmean = *(const f32x4*)&bm[kx * MDIM + hh * 16 + lhi * 4];
  const f32x4 blv   = *(const f32x4*)&bv[kx * MDIM + hh * 16 + lhi * 4];
  f32x4 bgv = {0.f, 0.f, 0.f, 0.f};
  if (wv < 4) bgv = *(const f32x4*)&bg[(lhi & 1) * 4];

  // W fragments (A-operand, transposed MFMA): ct 0 = mean, 1 = logvar;
  // cols = hh*16 + l15; k = lhi*8 + i.  8 frags = 32 regs.
  bf16x8 bfrag[2][4];
  #pragma unroll
  for (int ct = 0; ct < 2; ++ct) {
    const float* W = (ct ? Wv : Wm) + (size_t)kx * (DX * MDIM);
    const int mcol = hh * 16 + l15;
    #pragma unroll
    for (int kk = 0; kk < 4; ++kk) {
      bf16x8 tmp;
      #pragma unroll
      for (int i = 0; i < 8; ++i)
        tmp[i] = (__bf16)W[(kk * 32 + lhi * 8 + i) * MDIM + mcol];
      bfrag[ct][kk] = tmp;
    }
  }
  // Gate weights -> LDS (one wave; rows >= KEXP zero-padded)
  if (wv == 15) {
    #pragma unroll
    for (int kk = 0; kk < 2; ++kk) {
      bf16x8 tmp;
      #pragma unroll
      for (int i = 0; i < 8; ++i) {
        const int d = kk * 32 + lhi * 8 + i;
        tmp[i] = (__bf16)((l15 < KEXP) ? Wg[d * KEXP + l15] : 0.f);
      }
      *(bf16x8*)((char*)wg_lds + (kk * 64 + lane) * 16) = tmp;
    }
  }

  // prologue drain (once): tile-0 DMA + wg_lds visible
  asm volatile("s_waitcnt vmcnt(0) lgkmcnt(0)" ::: "memory");
  __builtin_amdgcn_s_barrier();
  __builtin_amdgcn_sched_barrier(0);

  const int grt = wv & 1;        // gate sample-half (waves 0-3)
  float loss_acc = 0.f;
  const float HL2PI = 0.91893853320467274f;   // 0.5*log(2*pi)

  for (int it = 0; it < TPB; ++it) {
    const int cur = it & 1;

    // issue next-tile DMA, then counted wait: own new batch stays in flight
    issue_batch(first + ((it + 1 < TPB) ? it + 1 : it), cur ^ 1);
    if (wv < 12) asm volatile("s_waitcnt vmcnt(2)" ::: "memory");
    else         asm volatile("s_waitcnt vmcnt(1)" ::: "memory");
    __builtin_amdgcn_s_barrier();
    __builtin_amdgcn_sched_barrier(0);

    // ---- gate MFMA (waves 0-3; reads ts2[cur]; overlaps expert phase) ----
    f32x4 lgv = {0.f, 0.f, 0.f, 0.f};
    if (wv < 4) {
      const float* tc = ts2[cur];
      const int rb = (grt * 16 + l15) * DT;
      f32x4 g = {0.f, 0.f, 0.f, 0.f};
      #pragma unroll
      for (int kk = 0; kk < 2; ++kk) {
        const f32x4 f0 = *(const f32x4*)&tc[rb + kk * 32 + (((lhi * 2 + 0) ^ swz) << 2)];
        const f32x4 f1 = *(const f32x4*)&tc[rb + kk * 32 + (((lhi * 2 + 1) ^ swz) << 2)];
        const bf16x8 wf = *(const bf16x8*)((const char*)wg_lds + (kk * 64 + lane) * 16);
        g = MFMA16(wf, cvt8(f0, f1), g);
      }
      #pragma unroll
      for (int j = 0; j < 4; ++j) lgv[j] = g[j] + bgv[j];
    }

    // ---- expert MFMAs + half-column Gaussian-LL ----
    const float* xc = xs2[cur];
    const float* yc = ys2[cur];
    #pragma unroll
    for (int rt = 0; rt < 2; ++rt) {
      const int rr = rt * 16 + l15;     // sample (B-col = l15)
      const int rbase = rr * DX;
      f32x4 acc0 = bmean, acc1 = blv;
      #pragma unroll
      for (int kk = 0; kk < 4; ++kk) {
        const f32x4 f0 = *(const f32x4*)&xc[rbase + kk * 32 + (((lhi * 2 + 0) ^ swz) << 2)];
        const f32x4 f1 = *(const f32x4*)&xc[rbase + kk * 32 + (((lhi * 2 + 1) ^ swz) << 2)];
        const bf16x8 xf = cvt8(f0, f1);
        acc0 = MFMA16(bfrag[0][kk], xf, acc0);
        acc1 = MFMA16(bfrag[1][kk], xf, acc1);
      }
      // D: col = l15 = sample, row = lhi*4+j = m (within half hh)
      const int sy = (hh * 4 + lhi) ^ (rr & 7);
      const f32x4 y4 = *(const f32x4*)&yc[rr * 32 + sy * 4];
      float part = 0.f;
      #pragma unroll
      for (int j = 0; j < 4; ++j) {
        const float d = y4[j] - acc0[j];
        part += d * d * (0.5f * __expf(-acc1[j])) + 0.5f * acc1[j];
      }
      part += __shfl_xor(part, 16);
      part += __shfl_xor(part, 32);
      if (lhi == 0) llp[rr * 20 + hh * 8 + kx] = -(part + 16.0f * HL2PI);
    }

    B_LDS();    // llp visible; all cur-buffer reads complete

    // ---- LSE over experts (waves 0-3): in-lane over 4 k's + 1 shfl ----
    if (wv < 4) {
      const int rr = grt * 16 + l15;
      const f32x4 lvA = *(const f32x4*)&llp[rr * 20 + (lhi & 1) * 4];
      const f32x4 lvB = *(const f32x4*)&llp[rr * 20 + 8 + (lhi & 1) * 4];
      f32x4 a4;
      #pragma unroll
      for (int j = 0; j < 4; ++j) a4[j] = lgv[j] + lvA[j] + lvB[j];
      float mg = fmaxf(fmaxf(lgv[0], lgv[1]), fmaxf(lgv[2], lgv[3]));
      float ma = fmaxf(fmaxf(a4[0], a4[1]), fmaxf(a4[2], a4[3]));
      mg = fmaxf(mg, __shfl_xor(mg, 16));
      ma = fmaxf(ma, __shfl_xor(ma, 16));
      float eg = __expf(lgv[0] - mg) + __expf(lgv[1] - mg)
               + __expf(lgv[2] - mg) + __expf(lgv[3] - mg);
      float ea = __expf(a4[0] - ma) + __expf(a4[1] - ma)
               + __expf(a4[2] - ma) + __expf(a4[3] - ma);
      eg += __shfl_xor(eg, 16);
      ea += __shfl_xor(ea, 16);
      if (wv < 2 && lhi == 0)
        loss_acc += (mg + __logf(eg)) - (ma + __logf(ea));
    }
  }

  // block reduction of loss
  loss_acc += __shfl_xor(loss_acc, 1);
  loss_acc += __shfl_xor(loss_acc, 2);
  loss_acc += __shfl_xor(loss_acc, 4);
  loss_acc += __shfl_xor(loss_acc, 8);
  loss_acc += __shfl_xor(loss_acc, 16);
  loss_acc += __shfl_xor(loss_acc, 32);
  if (lane == 0) red_s[wv] = loss_acc;
  __syncthreads();
  if (tid == 0) {
    float s = 0.f;
    #pragma unroll
    for (int w = 0; w < 16; ++w) s += red_s[w];
    if (partials) partials[blockIdx.x] = s;
    else atomicAdd(out_atomic, s);
  }
}

__global__ void mdn_reg(const float* __restrict__ Wm, const float* __restrict__ Wv,
                        const float* __restrict__ Wg, float* __restrict__ partials,
                        float* __restrict__ out_atomic)
{
  __shared__ float red[4];
  const int gid = blockIdx.x * 256 + threadIdx.x;
  const int stride = 64 * 256;
  float s = 0.f;
  for (int i = gid; i < DX * MDIM * KEXP; i += stride) { float w = Wm[i]; s += w * w; }
  for (int i = gid; i < DX * MDIM * KEXP; i += stride) { float w = Wv[i]; s += w * w; }
  for (int i = gid; i < DT * KEXP; i += stride)        { float w = Wg[i]; s += w * w; }
  s += __shfl_xor(s, 1);
  s += __shfl_xor(s, 2);
  s += __shfl_xor(s, 4);
  s += __shfl_xor(s, 8);
  s += __shfl_xor(s, 16);
  s += __shfl_xor(s, 32);
  if ((threadIdx.x & 63) == 0) red[threadIdx.x >> 6] = s;
  __syncthreads();
  if (threadIdx.x == 0) {
    float b = red[0] + red[1] + red[2] + red[3];
    if (partials) partials[GRID_MAIN + blockIdx.x] = b;
    else atomicAdd(out_atomic, b);
  }
}

__global__ void mdn_final(const float* __restrict__ partials, float* __restrict__ out)
{
  __shared__ float red[4];
  float s = 0.f;
  for (int i = threadIdx.x; i < GRID_MAIN + 64; i += 256) s += partials[i];
  s += __shfl_xor(s, 1);
  s += __shfl_xor(s, 2);
  s += __shfl_xor(s, 4);
  s += __shfl_xor(s, 8);
  s += __shfl_xor(s, 16);
  s += __shfl_xor(s, 32);
  if ((threadIdx.x & 63) == 0) red[threadIdx.x >> 6] = s;
  __syncthreads();
  if (threadIdx.x == 0) out[0] = red[0] + red[1] + red[2] + red[3];
}

extern "C" void kernel_launch(void* const* d_in, const int* in_sizes, int n_in,
                              void* d_out, int out_size, void* d_ws, size_t ws_size,
                              hipStream_t stream)
{
  const float* x  = (const float*)d_in[0];
  const float* t  = (const float*)d_in[1];
  const float* y  = (const float*)d_in[2];
  const float* Wm = (const float*)d_in[3];
  const float* bm = (const float*)d_in[4];
  const float* Wv = (const float*)d_in[5];
  const float* bv = (const float*)d_in[6];
  const float* Wg = (const float*)d_in[7];
  const float* bg = (const float*)d_in[8];
  float* out = (float*)d_out;

  if (ws_size >= (GRID_MAIN + 64) * sizeof(float)) {
    float* partials = (float*)d_ws;
    mdn_main<<<GRID_MAIN, THREADS, 0, stream>>>(x, t, y, Wm, bm, Wv, bv, Wg, bg,
                                                partials, nullptr);
    mdn_reg<<<64, 256, 0, stream>>>(Wm, Wv, Wg, partials, nullptr);
    mdn_final<<<1, 256, 0, stream>>>(partials, out);
  } else {
    hipMemsetAsync(out, 0, sizeof(float), stream);
    mdn_main<<<GRID_MAIN, THREADS, 0, stream>>>(x, t, y, Wm, bm, Wv, bv, Wg, bg,
                                                nullptr, out);
    mdn_reg<<<64, 256, 0, stream>>>(Wm, Wv, Wg, nullptr, out);
  }
}

// Round 13
// 142.157 us; speedup vs baseline: 1.3170x; 1.2932x over previous
//
#include <hip/hip_runtime.h>
#include <hip/hip_bf16.h>

// MDN NLL, fully fused. N=524288 Dx=128 Dt=64 M=32 K=8.
// Memory-bound target: 470 MB reads -> ~75us floor at 6.3 TB/s.
// R13 = R10 (best, 150us) + ONE change: single lgkm barrier per iter.
//   llp double-buffered; gate MFMA hoisted pre-barrier (ts[cur] visible
//   since last barrier); commit(next) ends region A; LSE post-barrier.
//   Waves 4-15 skip LSE and run ahead into the next tile's MFMAs.
// R10 carried: column-split 16 waves (kx=wv&7, hh=wv>>3), bfrag=32 regs,
//   transposed MFMA, reg-staged bf16 x/t tiles + f32 y tile (bf16 tiles =
//   half the ds_read volume of R12's f32 DMA tiles -> half the conflicts),
//   involution chunk swizzle, gate+LSE on waves 0-3.
// R11/R12 lessons: y direct-in-epilogue exposes latency; f32 LDS tiles
//   double conflicts (18.9M); spill (~41MB) is structural at the hard
//   128-unified cap, not staging-register-driven.

#define NN 524288
#define DX 128
#define DT 64
#define MDIM 32
#define KEXP 8
#define TILE_R 32
#define THREADS 1024
#define GRID_MAIN 512
#define TILES_TOTAL (NN / TILE_R)        // 16384
#define TPB (TILES_TOTAL / GRID_MAIN)    // 32

typedef __bf16 bf16x8 __attribute__((ext_vector_type(8)));
typedef float f32x4 __attribute__((ext_vector_type(4)));

__device__ __forceinline__ bf16x8 cvt8(const f32x4 a, const f32x4 b) {
  bf16x8 r;
  r[0] = (__bf16)a[0]; r[1] = (__bf16)a[1]; r[2] = (__bf16)a[2]; r[3] = (__bf16)a[3];
  r[4] = (__bf16)b[0]; r[5] = (__bf16)b[1]; r[6] = (__bf16)b[2]; r[7] = (__bf16)b[3];
  return r;
}

#define MFMA16(a, b, c) __builtin_amdgcn_mfma_f32_16x16x32_bf16(a, b, c, 0, 0, 0)

// LDS-only barrier: global loads stay in flight across it (rule 18 fence).
#define B_LDS() do { \
  asm volatile("s_waitcnt lgkmcnt(0)" ::: "memory"); \
  __builtin_amdgcn_s_barrier(); \
  __builtin_amdgcn_sched_barrier(0); } while (0)

__global__ __launch_bounds__(THREADS, 4) void mdn_main(
    const float* __restrict__ x, const float* __restrict__ t,
    const float* __restrict__ y, const float* __restrict__ Wm,
    const float* __restrict__ bm, const float* __restrict__ Wv,
    const float* __restrict__ bv, const float* __restrict__ Wg,
    const float* __restrict__ bg, float* __restrict__ partials,
    float* __restrict__ out_atomic)
{
  __shared__ __align__(16) unsigned short xs_l[2][TILE_R * DX];   // bf16 2x8KB
  __shared__ __align__(16) unsigned short ts_l[2][TILE_R * DT];   // bf16 2x4KB
  __shared__ __align__(16) float ys_l[2][TILE_R * MDIM];          // f32 2x4KB
  __shared__ __align__(16) unsigned short wg_lds[2 * 64 * 8];     // 2KB
  __shared__ float llp[2][TILE_R * 20];                           // 5KB dbuf
  __shared__ float red_s[16];

  const int tid = threadIdx.x;
  const int lane = tid & 63;
  const int wv = tid >> 6;        // 0..15
  const int l15 = lane & 15;
  const int lhi = lane >> 4;      // 0..3
  const int kx = wv & 7;          // expert
  const int hh = wv >> 3;         // column half (m-cols hh*16 .. +16)

  // ---- staging role geometry (involution swizzle: slot s holds global
  // chunk g = s ^ (row&7); readers use the same XOR) ----
  int st_ldsoff;                  // byte offset within destination buffer
  const float* st_base;
  int st_stride;                  // floats per tile
  if (tid < 512) {                // x: 32 rows x 16 chunks (16B bf16 out)
    const int r = tid >> 4, s = tid & 15, g = s ^ (r & 7);
    st_base = x + (size_t)r * DX + g * 8;
    st_stride = TILE_R * DX;
    st_ldsoff = r * 256 + s * 16;
  } else if (tid < 768) {         // t: 32 rows x 8 chunks
    const int u = tid - 512, r = u >> 3, s = u & 7, g = s ^ (r & 7);
    st_base = t + (size_t)r * DT + g * 8;
    st_stride = TILE_R * DT;
    st_ldsoff = r * 128 + s * 16;
  } else {                        // y: 32 rows x 8 chunks (f32x4 out)
    const int u = tid - 768, r = u >> 3, s = u & 7, g = s ^ (r & 7);
    st_base = y + (size_t)r * MDIM + g * 4;
    st_stride = TILE_R * MDIM;
    st_ldsoff = r * 128 + s * 16;
  }

  f32x4 sa, sb;
  auto issue = [&](int tile) {
    const float* p = st_base + (size_t)tile * st_stride;
    sa = *(const f32x4*)p;
    if (tid < 768) sb = *(const f32x4*)(p + 4);
  };
  auto commit = [&](int buf) {
    if (tid < 512)      *(bf16x8*)((char*)xs_l[buf] + st_ldsoff) = cvt8(sa, sb);
    else if (tid < 768) *(bf16x8*)((char*)ts_l[buf] + st_ldsoff) = cvt8(sa, sb);
    else                *(f32x4*)((char*)ys_l[buf] + st_ldsoff) = sa;
  };

  const int first = blockIdx.x * TPB;
  issue(first);    // tile-0 loads in flight under the weight prologue

  // biases once, direct from global: lane's 4 m's = hh*16 + lhi*4 + j
  const f32x4 bmean = *(const f32x4*)&bm[kx * MDIM + hh * 16 + lhi * 4];
  const f32x4 blv   = *(const f32x4*)&bv[kx * MDIM + hh * 16 + lhi * 4];
  f32x4 bgv = {0.f, 0.f, 0.f, 0.f};
  if (wv < 4) bgv = *(const f32x4*)&bg[(lhi & 1) * 4];

  // W fragments (A-operand, transposed MFMA): ct 0 = mean, 1 = logvar;
  // cols = hh*16 + l15; k = lhi*8 + i.  8 frags = 32 regs.
  bf16x8 bfrag[2][4];
  #pragma unroll
  for (int ct = 0; ct < 2; ++ct) {
    const float* W = (ct ? Wv : Wm) + (size_t)kx * (DX * MDIM);
    const int mcol = hh * 16 + l15;
    #pragma unroll
    for (int kk = 0; kk < 4; ++kk) {
      bf16x8 tmp;
      #pragma unroll
      for (int i = 0; i < 8; ++i)
        tmp[i] = (__bf16)W[(kk * 32 + lhi * 8 + i) * MDIM + mcol];
      bfrag[ct][kk] = tmp;
    }
  }
  // Gate weights -> LDS (one wave; rows >= KEXP zero-padded)
  if (wv == 15) {
    #pragma unroll
    for (int kk = 0; kk < 2; ++kk) {
      bf16x8 tmp;
      #pragma unroll
      for (int i = 0; i < 8; ++i) {
        const int d = kk * 32 + lhi * 8 + i;
        tmp[i] = (__bf16)((l15 < KEXP) ? Wg[d * KEXP + l15] : 0.f);
      }
      *(bf16x8*)((char*)wg_lds + (kk * 64 + lane) * 16) = tmp;
    }
  }

  commit(0);
  B_LDS();        // tile 0 + wg visible

  const int grt = wv & 1;          // gate sample-half (waves 0..3)
  float loss_acc = 0.f;
  const float HL2PI = 0.91893853320467274f;   // 0.5*log(2*pi)

  for (int it = 0; it < TPB; ++it) {
    const int cur = it & 1;
    issue(first + ((it + 1 < TPB) ? it + 1 : it));   // next tile, early

    // ---- gate MFMA (waves 0-3; ts[cur] visible since last barrier) ----
    f32x4 lgv = {0.f, 0.f, 0.f, 0.f};
    if (wv < 4) {
      const int rr = grt * 16 + l15;
      const int r7 = rr & 7;
      f32x4 g = {0.f, 0.f, 0.f, 0.f};
      #pragma unroll
      for (int kk = 0; kk < 2; ++kk) {
        const int s = (kk * 4 + lhi) ^ r7;
        const bf16x8 tf = *(const bf16x8*)((const char*)ts_l[cur] + rr * 128 + s * 16);
        const bf16x8 wf = *(const bf16x8*)((const char*)wg_lds + (kk * 64 + lane) * 16);
        g = MFMA16(wf, tf, g);
      }
      #pragma unroll
      for (int j = 0; j < 4; ++j) lgv[j] = g[j] + bgv[j];
    }

    // ---- expert MFMAs + half-column Gaussian-LL ----
    const unsigned short* xc = xs_l[cur];
    const float* yc = ys_l[cur];
    #pragma unroll
    for (int rt = 0; rt < 2; ++rt) {
      const int rr = rt * 16 + l15;     // sample (B-col = l15)
      const int r7 = rr & 7;
      f32x4 acc0 = bmean, acc1 = blv;
      #pragma unroll
      for (int kk = 0; kk < 4; ++kk) {
        const int s = (kk * 4 + lhi) ^ r7;
        const bf16x8 af = *(const bf16x8*)((const char*)xc + rr * 256 + s * 16);
        acc0 = MFMA16(bfrag[0][kk], af, acc0);
        acc1 = MFMA16(bfrag[1][kk], af, acc1);
      }
      // D: col = l15 = sample, row = lhi*4+j = m (within half hh)
      const int sy = (hh * 4 + lhi) ^ r7;
      const f32x4 y4 = *(const f32x4*)&yc[rr * 32 + sy * 4];
      float part = 0.f;
      #pragma unroll
      for (int j = 0; j < 4; ++j) {
        const float d = y4[j] - acc0[j];
        part += d * d * (0.5f * __expf(-acc1[j])) + 0.5f * acc1[j];
      }
      part += __shfl_xor(part, 16);
      part += __shfl_xor(part, 32);
      if (lhi == 0) llp[cur][rr * 20 + hh * 8 + kx] = -(part + 16.0f * HL2PI);
    }

    commit(cur ^ 1);   // write next tile into the other buffers
    B_LDS();           // the ONE barrier: llp[cur] + staged buffers visible

    // ---- LSE over experts (waves 0-3): in-lane over 4 k's + 1 shfl ----
    // Waves 4-15 fall straight through into the next iteration's MFMAs.
    if (wv < 4) {
      const int rr = grt * 16 + l15;
      const f32x4 lvA = *(const f32x4*)&llp[cur][rr * 20 + (lhi & 1) * 4];
      const f32x4 lvB = *(const f32x4*)&llp[cur][rr * 20 + 8 + (lhi & 1) * 4];
      f32x4 a4;
      #pragma unroll
      for (int j = 0; j < 4; ++j) a4[j] = lgv[j] + lvA[j] + lvB[j];
      float mg = fmaxf(fmaxf(lgv[0], lgv[1]), fmaxf(lgv[2], lgv[3]));
      float ma = fmaxf(fmaxf(a4[0], a4[1]), fmaxf(a4[2], a4[3]));
      mg = fmaxf(mg, __shfl_xor(mg, 16));
      ma = fmaxf(ma, __shfl_xor(ma, 16));
      float eg = __expf(lgv[0] - mg) + __expf(lgv[1] - mg)
               + __expf(lgv[2] - mg) + __expf(lgv[3] - mg);
      float ea = __expf(a4[0] - ma) + __expf(a4[1] - ma)
               + __expf(a4[2] - ma) + __expf(a4[3] - ma);
      eg += __shfl_xor(eg, 16);
      ea += __shfl_xor(ea, 16);
      if (wv < 2 && lhi == 0)
        loss_acc += (mg + __logf(eg)) - (ma + __logf(ea));
    }
  }

  // block reduction of loss
  loss_acc += __shfl_xor(loss_acc, 1);
  loss_acc += __shfl_xor(loss_acc, 2);
  loss_acc += __shfl_xor(loss_acc, 4);
  loss_acc += __shfl_xor(loss_acc, 8);
  loss_acc += __shfl_xor(loss_acc, 16);
  loss_acc += __shfl_xor(loss_acc, 32);
  if (lane == 0) red_s[wv] = loss_acc;
  __syncthreads();
  if (tid == 0) {
    float s = 0.f;
    #pragma unroll
    for (int w = 0; w < 16; ++w) s += red_s[w];
    if (partials) partials[blockIdx.x] = s;
    else atomicAdd(out_atomic, s);
  }
}

__global__ void mdn_reg(const float* __restrict__ Wm, const float* __restrict__ Wv,
                        const float* __restrict__ Wg, float* __restrict__ partials,
                        float* __restrict__ out_atomic)
{
  __shared__ float red[4];
  const int gid = blockIdx.x * 256 + threadIdx.x;
  const int stride = 64 * 256;
  float s = 0.f;
  for (int i = gid; i < DX * MDIM * KEXP; i += stride) { float w = Wm[i]; s += w * w; }
  for (int i = gid; i < DX * MDIM * KEXP; i += stride) { float w = Wv[i]; s += w * w; }
  for (int i = gid; i < DT * KEXP; i += stride)        { float w = Wg[i]; s += w * w; }
  s += __shfl_xor(s, 1);
  s += __shfl_xor(s, 2);
  s += __shfl_xor(s, 4);
  s += __shfl_xor(s, 8);
  s += __shfl_xor(s, 16);
  s += __shfl_xor(s, 32);
  if ((threadIdx.x & 63) == 0) red[threadIdx.x >> 6] = s;
  __syncthreads();
  if (threadIdx.x == 0) {
    float b = red[0] + red[1] + red[2] + red[3];
    if (partials) partials[GRID_MAIN + blockIdx.x] = b;
    else atomicAdd(out_atomic, b);
  }
}

__global__ void mdn_final(const float* __restrict__ partials, float* __restrict__ out)
{
  __shared__ float red[4];
  float s = 0.f;
  for (int i = threadIdx.x; i < GRID_MAIN + 64; i += 256) s += partials[i];
  s += __shfl_xor(s, 1);
  s += __shfl_xor(s, 2);
  s += __shfl_xor(s, 4);
  s += __shfl_xor(s, 8);
  s += __shfl_xor(s, 16);
  s += __shfl_xor(s, 32);
  if ((threadIdx.x & 63) == 0) red[threadIdx.x >> 6] = s;
  __syncthreads();
  if (threadIdx.x == 0) out[0] = red[0] + red[1] + red[2] + red[3];
}

extern "C" void kernel_launch(void* const* d_in, const int* in_sizes, int n_in,
                              void* d_out, int out_size, void* d_ws, size_t ws_size,
                              hipStream_t stream)
{
  const float* x  = (const float*)d_in[0];
  const float* t  = (const float*)d_in[1];
  const float* y  = (const float*)d_in[2];
  const float* Wm = (const float*)d_in[3];
  const float* bm = (const float*)d_in[4];
  const float* Wv = (const float*)d_in[5];
  const float* bv = (const float*)d_in[6];
  const float* Wg = (const float*)d_in[7];
  const float* bg = (const float*)d_in[8];
  float* out = (float*)d_out;

  if (ws_size >= (GRID_MAIN + 64) * sizeof(float)) {
    float* partials = (float*)d_ws;
    mdn_main<<<GRID_MAIN, THREADS, 0, stream>>>(x, t, y, Wm, bm, Wv, bv, Wg, bg,
                                                partials, nullptr);
    mdn_reg<<<64, 256, 0, stream>>>(Wm, Wv, Wg, partials, nullptr);
    mdn_final<<<1, 256, 0, stream>>>(partials, out);
  } else {
    hipMemsetAsync(out, 0, sizeof(float), stream);
    mdn_main<<<GRID_MAIN, THREADS, 0, stream>>>(x, t, y, Wm, bm, Wv, bv, Wg, bg,
                                                nullptr, out);
    mdn_reg<<<64, 256, 0, stream>>>(Wm, Wv, Wg, nullptr, out);
  }
}